// Round 2
// baseline (8857.807 us; speedup 1.0000x reference)
//
#include <hip/hip_runtime.h>

// ---------------------------------------------------------------------------
// 3-layer LSTM (B=64, T=512, IN=128, H=1024) + final FC, persistent kernel.
//
// R4: h-fragment reads now L2-CACHED (workgroup-scope relaxed atomics, no sc1)
//  + one agent-scope ACQUIRE fence (buffer_inv, no writeback walk) per step
//  right after the grid barrier. Rationale: rocprof showed FETCH 865MB /
//  WRITE 397MB per dispatch -> sc1 reads bypassed L2 entirely, so each of the
//  64 blocks per layer re-read the full 256KB B-operand from IC/HBM
//  (~37MB/step, 64x amplification) at far latency. With L2 caching, the 8
//  same-layer blocks on each XCD share one L2 copy (8x less far traffic,
//  ~200cy L2 hits that the 4-deep prefetch ring fully covers). Coherence:
//  publish stores stay RELAXED agent-scope sc1 (write-through past L2), and
//  the acquire fence invalidates stale L1/L2 lines before any read of the
//  new parity buffer.
//  - barrier: single monotonic counter, all-relaxed agent-scope (sc1) ops.
//  - combine: thread owns (1 batch x 4 consecutive j) -> one 8B publish.
//  - LDS pad 66 (2-way bank aliasing = free). 4-stage B prefetch ring.
// ---------------------------------------------------------------------------

#define TT 512
#define INF 128
#define HH 1024
#define NBLOCKS 192

typedef _Float16 f16x8 __attribute__((ext_vector_type(8)));
typedef float f32x4 __attribute__((ext_vector_type(4)));

// ws layout (bytes):
//   0       : ctrl[2]  (barrier monotonic counter, unused)
//   1024    : hbuf  3 layers x 2 parity x 32 kk x 4 bt x 64 lane x 8 f16 = 786432 B
//   787456  : xbuf  512 t x 4 kk x 4 bt x 64 lane x 8 f16 = 8388608 B
#define HBUF_OFF 1024
#define XBUF_OFF (1024 + 786432)

__device__ __forceinline__ float sigmf(float x) { return 1.f / (1.f + __expf(-x)); }
__device__ __forceinline__ float tanhfast(float x) { return 1.f - 2.f / (__expf(2.f * x) + 1.f); }

__global__ void init_kernel(unsigned* ctrl, unsigned* hbuf_u32, float* out, const float* fcb) {
  int tid = blockIdx.x * 256 + threadIdx.x;
  if (tid < 196608) hbuf_u32[tid] = 0u;          // zero hbuf (786432 B)
  if (blockIdx.x == 0) {
    if (threadIdx.x < 2) ctrl[threadIdx.x] = 0u; // barrier state
    if (threadIdx.x >= 64 && threadIdx.x < 128) out[threadIdx.x - 64] = fcb[0];
  }
}

// Pack x[b][t][k] (fp32) -> fp16 B-fragment layout [t][kk][bt][lane][8]
__global__ void packx_kernel(const float* __restrict__ x, _Float16* __restrict__ xbuf) {
  int tid = blockIdx.x * 256 + threadIdx.x; // [0, 524288)
  int t = tid >> 10;
  int rem = tid & 1023;
  int kk = rem >> 8;
  int bt = (rem >> 6) & 3;
  int lane = rem & 63;
  int b = bt * 16 + (lane & 15);
  int k = kk * 32 + (lane >> 4) * 8;
  const float* src = x + ((size_t)b * TT + t) * INF + k;
  f16x8 v;
#pragma unroll
  for (int j = 0; j < 8; ++j) v[j] = (_Float16)src[j];
  ((f16x8*)xbuf)[tid] = v;
}

// L2-cached 16B fragment load as two relaxed 8B atomics (WORKGROUP scope:
// plain global_load_dwordx2, no sc bits -> L1+L2 cached; still atomic in IR
// so it cannot be hoisted across the per-step acquire fence).
__device__ __forceinline__ f16x8 load_frag_cached(const unsigned long long* p) {
  union { unsigned long long u[2]; f16x8 v; } r;
  r.u[0] = __hip_atomic_load(p, __ATOMIC_RELAXED, __HIP_MEMORY_SCOPE_WORKGROUP);
  r.u[1] = __hip_atomic_load(p + 1, __ATOMIC_RELAXED, __HIP_MEMORY_SCOPE_WORKGROUP);
  return r.v;
}

// Load the 4 bt B-fragments for global k-chunk kk.
__device__ __forceinline__ void loadB(f16x8 bf[4], int layer, int kk, int t, int rp,
                                      const f16x8* __restrict__ xb8,
                                      const unsigned long long* __restrict__ hb_u,
                                      int lane) {
  if (layer == 0 && kk < 4) {
    const f16x8* bsrc = xb8 + (size_t)t * 1024 + (size_t)kk * 256;
#pragma unroll
    for (int bt = 0; bt < 4; ++bt) bf[bt] = bsrc[bt * 64 + lane];
  } else {
    int buf, kidx;
    if (layer == 0) { buf = rp; kidx = kk - 4; }
    else if (layer == 1) {
      if (kk < 32) { buf = rp; kidx = kk; } else { buf = 2 + rp; kidx = kk - 32; }
    } else {
      if (kk < 32) { buf = 2 + rp; kidx = kk; } else { buf = 4 + rp; kidx = kk - 32; }
    }
#pragma unroll
    for (int bt = 0; bt < 4; ++bt)
      bf[bt] = load_frag_cached(hb_u + ((size_t)buf * 8192 + kidx * 256 + bt * 64 + lane) * 2);
  }
}

__global__ void __launch_bounds__(256, 1)
lstm_main(const float* __restrict__ Wih0, const float* __restrict__ Wih1,
          const float* __restrict__ Wih2, const float* __restrict__ Whh,
          const float* __restrict__ bih, const float* __restrict__ bhh,
          const float* __restrict__ fcw, float* __restrict__ out,
          unsigned* __restrict__ ctrl, _Float16* __restrict__ hbuf,
          const _Float16* __restrict__ xbuf) {
  const int blk = blockIdx.x;
  const int layer = blk >> 6;
  const int cu = blk & 63;
  const int tid = threadIdx.x;
  const int wave = tid >> 6;
  const int lane = tid & 63;
  const int m = lane & 15;   // A-frag row within 16 (j), D-frag col (batch)
  const int q = lane >> 4;   // k-quad
  const int hid0 = cu << 4;  // 16 hidden units per block

  const int KW = (layer == 0) ? 9 : 16;  // K-steps (32 wide) per wave
  const int kk0 = wave * KW;

  __shared__ float part[4][4][16][66];  // [wave][gate][j][batch], pad 66 (2-way free)
  __shared__ float fcacc[64];

  // ---- one-time: load weights into A-fragments (registers, fp16) ----
  f16x8 fz;
#pragma unroll
  for (int j = 0; j < 8; ++j) fz[j] = (_Float16)0.f;

  f16x8 afrag[4][16];
#pragma unroll
  for (int g = 0; g < 4; ++g) {
#pragma unroll
    for (int kkl = 0; kkl < 16; ++kkl) {
      afrag[g][kkl] = fz;
      if (kkl < KW) {
        int kk = kk0 + kkl;
        int row = g * HH + hid0 + m;
        const float* src;
        if (layer == 0) {
          src = (kk < 4) ? (Wih0 + (size_t)row * INF + kk * 32)
                         : (Whh + (size_t)row * HH + (kk - 4) * 32);
        } else if (layer == 1) {
          src = (kk < 32) ? (Wih1 + (size_t)row * HH + kk * 32)
                          : (Whh + (size_t)(4 * HH) * HH + (size_t)row * HH + (kk - 32) * 32);
        } else {
          src = (kk < 32) ? (Wih2 + (size_t)row * HH + kk * 32)
                          : (Whh + (size_t)(8 * HH) * HH + (size_t)row * HH + (kk - 32) * 32);
        }
        src += q * 8;
        f16x8 v;
#pragma unroll
        for (int j = 0; j < 8; ++j) v[j] = (_Float16)src[j];
        afrag[g][kkl] = v;
      }
    }
  }

  // ---- combine mapping: thread -> (batch bq = tid&63, j in [j4, j4+4)) ----
  const int bq = tid & 63;
  const int j4 = wave * 4;  // wave w combines j rows 4w..4w+3 (within the 16)
  float biasv[4][4];        // [gate][i]
#pragma unroll
  for (int g = 0; g < 4; ++g)
#pragma unroll
    for (int i = 0; i < 4; ++i) {
      int row = layer * 4 * HH + g * HH + hid0 + j4 + i;
      biasv[g][i] = bih[row] + bhh[row];
    }
  float fcwv[4];
#pragma unroll
  for (int i = 0; i < 4; ++i) fcwv[i] = (layer == 2) ? fcw[hid0 + j4 + i] : 0.f;
  float cst[4] = {0.f, 0.f, 0.f, 0.f};

  // publish address (all 4 j's of this thread share kkp/qp/8B-slot)
  const int jg = hid0 + j4;
  const int kkp = jg >> 5;
  const int qp = (jg >> 3) & 3;
  const int slot = (j4 & 7) >> 2;  // 0 or 1: which 8B half of the 16B chunk
  const int btp = bq >> 4;
  const int lanep = (bq & 15) + (qp << 4);

  const f16x8* xb8 = (const f16x8*)xbuf;
  const unsigned long long* hb_u = (const unsigned long long*)hbuf;
  unsigned long long* hb_w = (unsigned long long*)hbuf;

  const f32x4 zacc = {0.f, 0.f, 0.f, 0.f};

  for (int s = 0; s < TT + 2; ++s) {
    const int t = s - layer;
    const bool active = (t >= 0) && (t < TT);
    if (active) {
      const int rp = (s + 1) & 1;  // read parity (written last iteration)
      const int wp = s & 1;        // write parity

      f32x4 acc[4][4];
#pragma unroll
      for (int g = 0; g < 4; ++g)
#pragma unroll
        for (int bt = 0; bt < 4; ++bt) acc[g][bt] = zacc;

      // ---- K loop with 4-stage B prefetch ring (static stage indexing) ----
      f16x8 bf0[4], bf1[4], bf2[4], bf3[4];
      loadB(bf0, layer, kk0 + 0, t, rp, xb8, hb_u, lane);
      loadB(bf1, layer, kk0 + 1, t, rp, xb8, hb_u, lane);
      loadB(bf2, layer, kk0 + 2, t, rp, xb8, hb_u, lane);
      loadB(bf3, layer, kk0 + 3, t, rp, xb8, hb_u, lane);

#define LSTM_STEP(KKL, BUF)                                                   \
      if ((KKL) < KW) {                                                       \
        _Pragma("unroll")                                                     \
        for (int g = 0; g < 4; ++g) {                                         \
          _Pragma("unroll")                                                   \
          for (int bt = 0; bt < 4; ++bt)                                      \
            acc[g][bt] = __builtin_amdgcn_mfma_f32_16x16x32_f16(              \
                afrag[g][(KKL)], BUF[bt], acc[g][bt], 0, 0, 0);               \
        }                                                                     \
        if ((KKL) + 4 < KW)                                                   \
          loadB(BUF, layer, kk0 + (KKL) + 4, t, rp, xb8, hb_u, lane);         \
      }

      LSTM_STEP(0, bf0)
      LSTM_STEP(1, bf1)
      LSTM_STEP(2, bf2)
      LSTM_STEP(3, bf3)
      LSTM_STEP(4, bf0)
      LSTM_STEP(5, bf1)
      LSTM_STEP(6, bf2)
      LSTM_STEP(7, bf3)
      LSTM_STEP(8, bf0)
      LSTM_STEP(9, bf1)
      LSTM_STEP(10, bf2)
      LSTM_STEP(11, bf3)
      LSTM_STEP(12, bf0)
      LSTM_STEP(13, bf1)
      LSTM_STEP(14, bf2)
      LSTM_STEP(15, bf3)
#undef LSTM_STEP

      // partials -> LDS  (D layout: col=lane&15 (batch), row=q*4+r (j))
#pragma unroll
      for (int g = 0; g < 4; ++g)
#pragma unroll
        for (int bt = 0; bt < 4; ++bt)
#pragma unroll
          for (int r = 0; r < 4; ++r)
            part[wave][g][q * 4 + r][bt * 16 + m] = acc[g][bt][r];

      const bool do_fc = (layer == 2) && (t == TT - 1);
      if (do_fc && tid < 64) fcacc[tid] = 0.f;
      __syncthreads();

      // combine: sum 4 wave-partials, bias, nonlinearity, c update, publish h
      float pre[4][4];
#pragma unroll
      for (int g = 0; g < 4; ++g)
#pragma unroll
        for (int i = 0; i < 4; ++i) pre[g][i] = biasv[g][i];
#pragma unroll
      for (int w = 0; w < 4; ++w)
#pragma unroll
        for (int g = 0; g < 4; ++g)
#pragma unroll
          for (int i = 0; i < 4; ++i) pre[g][i] += part[w][g][j4 + i][bq];

      union { unsigned long long u; _Float16 h4[4]; } pk;
      float facc = 0.f;
#pragma unroll
      for (int i = 0; i < 4; ++i) {
        float ig = sigmf(pre[0][i]);
        float fg = sigmf(pre[1][i]);
        float gg = tanhfast(pre[2][i]);
        float og = sigmf(pre[3][i]);
        cst[i] = fg * cst[i] + ig * gg;
        float hv = og * tanhfast(cst[i]);
        pk.h4[i] = (_Float16)hv;
        facc += hv * fcwv[i];
      }
      unsigned long long* pub =
          hb_w + ((size_t)(((layer * 2 + wp) * 32 + kkp) * 256 + btp * 64 + lanep)) * 2 + slot;
      __hip_atomic_store(pub, pk.u, __ATOMIC_RELAXED, __HIP_MEMORY_SCOPE_AGENT);

      if (do_fc) {
        atomicAdd(&fcacc[bq], facc);
        __syncthreads();
        if (tid < 64) atomicAdd(&out[tid], fcacc[tid]);
      }
    }

    // ---- grid barrier: all-relaxed monotonic counter ----
    __builtin_amdgcn_s_waitcnt(0);  // each wave drains its publish stores (sc1 -> IC/HBM)
    __syncthreads();                // all waves drained before tid0 signals
    if (tid == 0) {
      const unsigned target = (unsigned)(s + 1) * NBLOCKS;
      __hip_atomic_fetch_add(&ctrl[0], 1u, __ATOMIC_RELAXED, __HIP_MEMORY_SCOPE_AGENT);
      while (__hip_atomic_load(&ctrl[0], __ATOMIC_RELAXED, __HIP_MEMORY_SCOPE_AGENT) < target) {
        __builtin_amdgcn_s_sleep(2);
      }
    }
    __syncthreads();
    // Acquire: invalidate stale L1/L2 lines (no writeback walk) so the
    // L2-cached hbuf reads of the next step see this step's sc1 publishes.
    __builtin_amdgcn_fence(__ATOMIC_ACQUIRE, "agent");
  }
}

extern "C" void kernel_launch(void* const* d_in, const int* in_sizes, int n_in,
                              void* d_out, int out_size, void* d_ws, size_t ws_size,
                              hipStream_t stream) {
  const float* x    = (const float*)d_in[0];
  const float* Wih0 = (const float*)d_in[1];
  const float* Wih1 = (const float*)d_in[2];
  const float* Wih2 = (const float*)d_in[3];
  const float* Whh  = (const float*)d_in[4];
  const float* bih  = (const float*)d_in[5];
  const float* bhh  = (const float*)d_in[6];
  const float* fcw  = (const float*)d_in[7];
  const float* fcb  = (const float*)d_in[8];
  float* out = (float*)d_out;

  char* ws = (char*)d_ws;
  unsigned* ctrl = (unsigned*)ws;
  _Float16* hbuf = (_Float16*)(ws + HBUF_OFF);
  _Float16* xbuf = (_Float16*)(ws + XBUF_OFF);

  init_kernel<<<768, 256, 0, stream>>>(ctrl, (unsigned*)hbuf, out, fcb);
  packx_kernel<<<2048, 256, 0, stream>>>(x, xbuf);
  lstm_main<<<NBLOCKS, 256, 0, stream>>>(Wih0, Wih1, Wih2, Whh, bih, bhh, fcw,
                                         out, ctrl, hbuf, xbuf);
}

// Round 7
// 5322.896 us; speedup vs baseline: 1.6641x; 1.6641x over previous
//
#include <hip/hip_runtime.h>

// ---------------------------------------------------------------------------
// 3-layer LSTM (B=64, T=512, IN=128, H=1024) + final FC, persistent kernel.
//
// R9 = R3 (proven, 6566us) + ONE change: h-fragment reads are single 16B
// IC-coherent loads (global_load_dwordx4 sc0 sc1) instead of two 8B
// agent-scope atomic loads at 16B lane-stride.
//  Theory: sc1 bypasses L1+L2, so R3's two strided 8B instructions each
//  fetch the SAME IC lines -> 2x fabric traffic (~96MB/step for 48MB of
//  demand). One dwordx4 halves instructions and line fetches on the
//  fabric-throughput-bound read path.
//  Mechanics: asm loads are invisible to the compiler waitcnt pass, so the
//  4-stage ring uses hand-counted LITERAL vmcnt (12/12/.../8/4/0) +
//  sched_barrier(0) after each wait (rule: hipcc hoists reg-only MFMA past
//  asm waitcnt otherwise). All counts are preprocessor literals -- no
//  template "n" constraints (R5-family crash suspect, bisected here).
//  EVERYTHING else (ws layout, barrier, combine, publish) is byte-identical
//  to R3. R5-family (census/staging/two-level barrier) is shelved until the
//  asm pattern is exonerated by this round.
// ---------------------------------------------------------------------------

#define TT 512
#define INF 128
#define HH 1024
#define NBLOCKS 192

typedef _Float16 f16x8 __attribute__((ext_vector_type(8)));
typedef float f32x4 __attribute__((ext_vector_type(4)));

// ws layout (bytes):
//   0       : ctrl[2]  (barrier monotonic counter, unused)
//   1024    : hbuf  3 layers x 2 parity x 32 kk x 4 bt x 64 lane x 8 f16 = 786432 B
//   787456  : xbuf  512 t x 4 kk x 4 bt x 64 lane x 8 f16 = 8388608 B
#define HBUF_OFF 1024
#define XBUF_OFF (1024 + 786432)

__device__ __forceinline__ float sigmf(float x) { return 1.f / (1.f + __expf(-x)); }
__device__ __forceinline__ float tanhfast(float x) { return 1.f - 2.f / (__expf(2.f * x) + 1.f); }

__global__ void init_kernel(unsigned* ctrl, unsigned* hbuf_u32, float* out, const float* fcb) {
  int tid = blockIdx.x * 256 + threadIdx.x;
  if (tid < 196608) hbuf_u32[tid] = 0u;          // zero hbuf (786432 B)
  if (blockIdx.x == 0) {
    if (threadIdx.x < 2) ctrl[threadIdx.x] = 0u; // barrier state
    if (threadIdx.x >= 64 && threadIdx.x < 128) out[threadIdx.x - 64] = fcb[0];
  }
}

// Pack x[b][t][k] (fp32) -> fp16 B-fragment layout [t][kk][bt][lane][8]
__global__ void packx_kernel(const float* __restrict__ x, _Float16* __restrict__ xbuf) {
  int tid = blockIdx.x * 256 + threadIdx.x; // [0, 524288)
  int t = tid >> 10;
  int rem = tid & 1023;
  int kk = rem >> 8;
  int bt = (rem >> 6) & 3;
  int lane = rem & 63;
  int b = bt * 16 + (lane & 15);
  int k = kk * 32 + (lane >> 4) * 8;
  const float* src = x + ((size_t)b * TT + t) * INF + k;
  f16x8 v;
#pragma unroll
  for (int j = 0; j < 8; ++j) v[j] = (_Float16)src[j];
  ((f16x8*)xbuf)[tid] = v;
}

// 16B IC-coherent load: bypass L1 (sc0) and L2 (sc1) -> reads IC-fresh h.
__device__ __forceinline__ f16x8 load_ic16(const void* p) {
  f16x8 v;
  asm volatile("global_load_dwordx4 %0, %1, off sc0 sc1" : "=&v"(v) : "v"(p) : "memory");
  return v;
}
// 16B cached load (read-only xbuf) -- asm so it shares the manual vmcnt ring.
__device__ __forceinline__ f16x8 load_ca16(const void* p) {
  f16x8 v;
  asm volatile("global_load_dwordx4 %0, %1, off" : "=&v"(v) : "v"(p) : "memory");
  return v;
}

__device__ __forceinline__ void loadB4_ic(f16x8 bf[4], const char* base, int lane) {
#pragma unroll
  for (int bt = 0; bt < 4; ++bt) bf[bt] = load_ic16(base + (size_t)(bt * 64 + lane) * 16);
}

// Layer-0 prefetch: kk<4 comes from cached xbuf, else IC hbuf. Both sides
// issue exactly 4 vmem ops (wave-uniform branch) so vmcnt counts stay exact.
__device__ __forceinline__ void pfL0(f16x8 bf[4], int kk, const char* xb, const char* bLo,
                                     int lane) {
  if (kk < 4) {
    const char* b = xb + (size_t)kk * 4096;
#pragma unroll
    for (int bt = 0; bt < 4; ++bt) bf[bt] = load_ca16(b + (size_t)(bt * 64 + lane) * 16);
  } else {
    const char* b = bLo + (size_t)(kk - 4) * 4096;
#pragma unroll
    for (int bt = 0; bt < 4; ++bt) bf[bt] = load_ic16(b + (size_t)(bt * 64 + lane) * 16);
  }
}

#define WAITV(N) asm volatile("s_waitcnt vmcnt(" #N ")" ::: "memory")
#define SB0 __builtin_amdgcn_sched_barrier(0)
#define MSTEP(KKL, BUF)                                                     \
  {                                                                         \
    _Pragma("unroll") for (int g = 0; g < 4; ++g) {                         \
      _Pragma("unroll") for (int bt = 0; bt < 4; ++bt)                      \
          acc[g][bt] = __builtin_amdgcn_mfma_f32_16x16x32_f16(              \
              afrag[g][KKL], BUF[bt], acc[g][bt], 0, 0, 0);                 \
    }                                                                       \
  }

// Layers 1/2: 16 K-steps, all IC; each wave's 16 steps stay inside one
// 32-chunk half, so the base pointer is wave-uniform.
__device__ __forceinline__ void kloop16(f32x4 acc[4][4], const f16x8 afrag[4][16], int kk0,
                                        const char* bLo, const char* bHi, int lane) {
  const char* wb = (kk0 < 32) ? bLo + (size_t)kk0 * 4096 : bHi + (size_t)(kk0 - 32) * 4096;
  f16x8 b0[4], b1[4], b2[4], b3[4];
  loadB4_ic(b0, wb + 0 * 4096, lane);
  loadB4_ic(b1, wb + 1 * 4096, lane);
  loadB4_ic(b2, wb + 2 * 4096, lane);
  loadB4_ic(b3, wb + 3 * 4096, lane);
  WAITV(12); SB0; MSTEP(0, b0);  loadB4_ic(b0, wb + 4 * 4096, lane);
  WAITV(12); SB0; MSTEP(1, b1);  loadB4_ic(b1, wb + 5 * 4096, lane);
  WAITV(12); SB0; MSTEP(2, b2);  loadB4_ic(b2, wb + 6 * 4096, lane);
  WAITV(12); SB0; MSTEP(3, b3);  loadB4_ic(b3, wb + 7 * 4096, lane);
  WAITV(12); SB0; MSTEP(4, b0);  loadB4_ic(b0, wb + 8 * 4096, lane);
  WAITV(12); SB0; MSTEP(5, b1);  loadB4_ic(b1, wb + 9 * 4096, lane);
  WAITV(12); SB0; MSTEP(6, b2);  loadB4_ic(b2, wb + 10 * 4096, lane);
  WAITV(12); SB0; MSTEP(7, b3);  loadB4_ic(b3, wb + 11 * 4096, lane);
  WAITV(12); SB0; MSTEP(8, b0);  loadB4_ic(b0, wb + 12 * 4096, lane);
  WAITV(12); SB0; MSTEP(9, b1);  loadB4_ic(b1, wb + 13 * 4096, lane);
  WAITV(12); SB0; MSTEP(10, b2); loadB4_ic(b2, wb + 14 * 4096, lane);
  WAITV(12); SB0; MSTEP(11, b3); loadB4_ic(b3, wb + 15 * 4096, lane);
  WAITV(12); SB0; MSTEP(12, b0);
  WAITV(8);  SB0; MSTEP(13, b1);
  WAITV(4);  SB0; MSTEP(14, b2);
  WAITV(0);  SB0; MSTEP(15, b3);
}

// Layer 0: 9 K-steps (4 x-chunks + 5..32 h-chunks split across waves).
__device__ __forceinline__ void kloop9(f32x4 acc[4][4], const f16x8 afrag[4][16], int kk0,
                                       const char* xb, const char* bLo, int lane) {
  f16x8 b0[4], b1[4], b2[4], b3[4];
  pfL0(b0, kk0 + 0, xb, bLo, lane);
  pfL0(b1, kk0 + 1, xb, bLo, lane);
  pfL0(b2, kk0 + 2, xb, bLo, lane);
  pfL0(b3, kk0 + 3, xb, bLo, lane);
  WAITV(12); SB0; MSTEP(0, b0); pfL0(b0, kk0 + 4, xb, bLo, lane);
  WAITV(12); SB0; MSTEP(1, b1); pfL0(b1, kk0 + 5, xb, bLo, lane);
  WAITV(12); SB0; MSTEP(2, b2); pfL0(b2, kk0 + 6, xb, bLo, lane);
  WAITV(12); SB0; MSTEP(3, b3); pfL0(b3, kk0 + 7, xb, bLo, lane);
  WAITV(12); SB0; MSTEP(4, b0); pfL0(b0, kk0 + 8, xb, bLo, lane);
  WAITV(12); SB0; MSTEP(5, b1);
  WAITV(8);  SB0; MSTEP(6, b2);
  WAITV(4);  SB0; MSTEP(7, b3);
  WAITV(0);  SB0; MSTEP(8, b0);
}

__global__ void __launch_bounds__(256, 1)
lstm_main(const float* __restrict__ Wih0, const float* __restrict__ Wih1,
          const float* __restrict__ Wih2, const float* __restrict__ Whh,
          const float* __restrict__ bih, const float* __restrict__ bhh,
          const float* __restrict__ fcw, float* __restrict__ out,
          unsigned* __restrict__ ctrl, _Float16* __restrict__ hbuf,
          const _Float16* __restrict__ xbuf) {
  const int blk = blockIdx.x;
  const int layer = blk >> 6;
  const int cu = blk & 63;
  const int tid = threadIdx.x;
  const int wave = tid >> 6;
  const int lane = tid & 63;
  const int m = lane & 15;   // A-frag row within 16 (j), D-frag col (batch)
  const int q = lane >> 4;   // k-quad
  const int hid0 = cu << 4;  // 16 hidden units per block

  const int KW = (layer == 0) ? 9 : 16;  // K-steps (32 wide) per wave
  const int kk0 = wave * KW;

  __shared__ float part[4][4][16][66];  // [wave][gate][j][batch], pad 66 (2-way free)
  __shared__ float fcacc[64];

  // ---- one-time: load weights into A-fragments (registers, fp16) ----
  f16x8 fz;
#pragma unroll
  for (int j = 0; j < 8; ++j) fz[j] = (_Float16)0.f;

  f16x8 afrag[4][16];
#pragma unroll
  for (int g = 0; g < 4; ++g) {
#pragma unroll
    for (int kkl = 0; kkl < 16; ++kkl) {
      afrag[g][kkl] = fz;
      if (kkl < KW) {
        int kk = kk0 + kkl;
        int row = g * HH + hid0 + m;
        const float* src;
        if (layer == 0) {
          src = (kk < 4) ? (Wih0 + (size_t)row * INF + kk * 32)
                         : (Whh + (size_t)row * HH + (kk - 4) * 32);
        } else if (layer == 1) {
          src = (kk < 32) ? (Wih1 + (size_t)row * HH + kk * 32)
                          : (Whh + (size_t)(4 * HH) * HH + (size_t)row * HH + (kk - 32) * 32);
        } else {
          src = (kk < 32) ? (Wih2 + (size_t)row * HH + kk * 32)
                          : (Whh + (size_t)(8 * HH) * HH + (size_t)row * HH + (kk - 32) * 32);
        }
        src += q * 8;
        f16x8 v;
#pragma unroll
        for (int j = 0; j < 8; ++j) v[j] = (_Float16)src[j];
        afrag[g][kkl] = v;
      }
    }
  }

  // ---- combine mapping: thread -> (batch bq = tid&63, j in [j4, j4+4)) ----
  const int bq = tid & 63;
  const int j4 = wave * 4;  // wave w combines j rows 4w..4w+3 (within the 16)
  float biasv[4][4];        // [gate][i]
#pragma unroll
  for (int g = 0; g < 4; ++g)
#pragma unroll
    for (int i = 0; i < 4; ++i) {
      int row = layer * 4 * HH + g * HH + hid0 + j4 + i;
      biasv[g][i] = bih[row] + bhh[row];
    }
  float fcwv[4];
#pragma unroll
  for (int i = 0; i < 4; ++i) fcwv[i] = (layer == 2) ? fcw[hid0 + j4 + i] : 0.f;
  float cst[4] = {0.f, 0.f, 0.f, 0.f};

  // publish address (all 4 j's of this thread share kkp/qp/8B-slot)
  const int jg = hid0 + j4;
  const int kkp = jg >> 5;
  const int qp = (jg >> 3) & 3;
  const int slot = (j4 & 7) >> 2;  // 0 or 1: which 8B half of the 16B chunk
  const int btp = bq >> 4;
  const int lanep = (bq & 15) + (qp << 4);

  const char* const hb = (const char*)hbuf;
  const char* const xbB = (const char*)xbuf;
  unsigned long long* hb_w = (unsigned long long*)hbuf;

  const f32x4 zacc = {0.f, 0.f, 0.f, 0.f};

  for (int s = 0; s < TT + 2; ++s) {
    const int t = s - layer;
    const bool active = (t >= 0) && (t < TT);
    if (active) {
      const int rp = (s + 1) & 1;  // read parity (written last iteration)
      const int wp = s & 1;        // write parity

      f32x4 acc[4][4];
#pragma unroll
      for (int g = 0; g < 4; ++g)
#pragma unroll
        for (int bt = 0; bt < 4; ++bt) acc[g][bt] = zacc;

      // ---- K loop: 4-stage ring, 16B IC loads, literal hand-counted vmcnt ----
      // hbuf image bases (131072 B per (layer,parity) image):
      if (layer == 0) {
        kloop9(acc, afrag, kk0, xbB + (size_t)t * 16384, hb + (size_t)rp * 131072, lane);
      } else if (layer == 1) {
        kloop16(acc, afrag, kk0, hb + (size_t)rp * 131072, hb + (size_t)(2 + rp) * 131072, lane);
      } else {
        kloop16(acc, afrag, kk0, hb + (size_t)(2 + rp) * 131072, hb + (size_t)(4 + rp) * 131072,
                lane);
      }

      // partials -> LDS  (D layout: col=lane&15 (batch), row=q*4+r (j))
#pragma unroll
      for (int g = 0; g < 4; ++g)
#pragma unroll
        for (int bt = 0; bt < 4; ++bt)
#pragma unroll
          for (int r = 0; r < 4; ++r)
            part[wave][g][q * 4 + r][bt * 16 + m] = acc[g][bt][r];

      const bool do_fc = (layer == 2) && (t == TT - 1);
      if (do_fc && tid < 64) fcacc[tid] = 0.f;
      __syncthreads();

      // combine: sum 4 wave-partials, bias, nonlinearity, c update, publish h
      float pre[4][4];
#pragma unroll
      for (int g = 0; g < 4; ++g)
#pragma unroll
        for (int i = 0; i < 4; ++i) pre[g][i] = biasv[g][i];
#pragma unroll
      for (int w = 0; w < 4; ++w)
#pragma unroll
        for (int g = 0; g < 4; ++g)
#pragma unroll
          for (int i = 0; i < 4; ++i) pre[g][i] += part[w][g][j4 + i][bq];

      union { unsigned long long u; _Float16 h4[4]; } pk;
      float facc = 0.f;
#pragma unroll
      for (int i = 0; i < 4; ++i) {
        float ig = sigmf(pre[0][i]);
        float fg = sigmf(pre[1][i]);
        float gg = tanhfast(pre[2][i]);
        float og = sigmf(pre[3][i]);
        cst[i] = fg * cst[i] + ig * gg;
        float hv = og * tanhfast(cst[i]);
        pk.h4[i] = (_Float16)hv;
        facc += hv * fcwv[i];
      }
      unsigned long long* pub =
          hb_w + ((size_t)(((layer * 2 + wp) * 32 + kkp) * 256 + btp * 64 + lanep)) * 2 + slot;
      __hip_atomic_store(pub, pk.u, __ATOMIC_RELAXED, __HIP_MEMORY_SCOPE_AGENT);

      if (do_fc) {
        atomicAdd(&fcacc[bq], facc);
        __syncthreads();
        if (tid < 64) atomicAdd(&out[tid], fcacc[tid]);
      }
    }

    // ---- grid barrier: all-relaxed monotonic counter (no cache flushes) ----
    __builtin_amdgcn_s_waitcnt(0);  // each wave drains its publish stores to IC
    __syncthreads();                // all waves drained before tid0 signals
    if (tid == 0) {
      const unsigned target = (unsigned)(s + 1) * NBLOCKS;
      __hip_atomic_fetch_add(&ctrl[0], 1u, __ATOMIC_RELAXED, __HIP_MEMORY_SCOPE_AGENT);
      while (__hip_atomic_load(&ctrl[0], __ATOMIC_RELAXED, __HIP_MEMORY_SCOPE_AGENT) < target) {
        __builtin_amdgcn_s_sleep(2);
      }
    }
    __syncthreads();
  }
}

extern "C" void kernel_launch(void* const* d_in, const int* in_sizes, int n_in,
                              void* d_out, int out_size, void* d_ws, size_t ws_size,
                              hipStream_t stream) {
  const float* x    = (const float*)d_in[0];
  const float* Wih0 = (const float*)d_in[1];
  const float* Wih1 = (const float*)d_in[2];
  const float* Wih2 = (const float*)d_in[3];
  const float* Whh  = (const float*)d_in[4];
  const float* bih  = (const float*)d_in[5];
  const float* bhh  = (const float*)d_in[6];
  const float* fcw  = (const float*)d_in[7];
  const float* fcb  = (const float*)d_in[8];
  float* out = (float*)d_out;

  char* ws = (char*)d_ws;
  unsigned* ctrl = (unsigned*)ws;
  _Float16* hbuf = (_Float16*)(ws + HBUF_OFF);
  _Float16* xbuf = (_Float16*)(ws + XBUF_OFF);

  init_kernel<<<768, 256, 0, stream>>>(ctrl, (unsigned*)hbuf, out, fcb);
  packx_kernel<<<2048, 256, 0, stream>>>(x, xbuf);
  lstm_main<<<NBLOCKS, 256, 0, stream>>>(Wih0, Wih1, Wih2, Whh, bih, bhh, fcw,
                                         out, ctrl, hbuf, xbuf);
}